// Round 1
// baseline (41.647 us; speedup 1.0000x reference)
//
#include <hip/hip_runtime.h>

// loss = (1/N) * sum_n clip(||x_n - c_{label_n}||^2, 1e-12, 1e12)  +  (C-1)*1e-12
// (all off-diagonal masked entries are exactly 0 -> clamp to 1e-12, N*(C-1) of them)

__global__ void center_loss_partial(const float* __restrict__ x,
                                    const float* __restrict__ centers,
                                    const int* __restrict__ labels,
                                    float* __restrict__ accum,
                                    int N) {
    const int gtid   = blockIdx.x * blockDim.x + threadIdx.x;
    const int wave   = gtid >> 6;
    const int lane   = threadIdx.x & 63;
    const int nwaves = (gridDim.x * blockDim.x) >> 6;

    float acc = 0.0f;
    for (int row = wave; row < N; row += nwaves) {
        const int c = labels[row];
        // D = 128 floats per row: each lane takes a float2 -> 64*8B = 512B coalesced
        const float2 xv = *reinterpret_cast<const float2*>(x + (size_t)row * 128 + lane * 2);
        const float2 cv = *reinterpret_cast<const float2*>(centers + (size_t)c * 128 + lane * 2);
        const float d0 = xv.x - cv.x;
        const float d1 = xv.y - cv.y;
        float d = d0 * d0 + d1 * d1;
        // wave-level reduction (64 lanes)
        #pragma unroll
        for (int off = 32; off; off >>= 1) d += __shfl_down(d, off, 64);
        if (lane == 0) acc += fminf(fmaxf(d, 1e-12f), 1e12f);
    }
    if (lane == 0) atomicAdd(accum, acc);
}

__global__ void center_loss_finalize(const float* __restrict__ accum,
                                     float* __restrict__ out,
                                     float invN, float floor_term) {
    if (threadIdx.x == 0 && blockIdx.x == 0) {
        out[0] = accum[0] * invN + floor_term;
    }
}

extern "C" void kernel_launch(void* const* d_in, const int* in_sizes, int n_in,
                              void* d_out, int out_size, void* d_ws, size_t ws_size,
                              hipStream_t stream) {
    const float* x       = (const float*)d_in[0];
    const float* centers = (const float*)d_in[1];
    const int*   labels  = (const int*)d_in[2];
    float* out   = (float*)d_out;
    float* accum = (float*)d_ws;

    const int D = 128;
    const int N = in_sizes[0] / D;   // 16384
    const int C = in_sizes[1] / D;   // 1024

    // zero the atomic accumulator (harness poisons d_ws once; we must init every call)
    hipMemsetAsync(accum, 0, sizeof(float), stream);

    const int block = 256;                 // 4 waves/block
    const int grid  = 512;                 // 2048 waves -> 8 rows per wave
    center_loss_partial<<<grid, block, 0, stream>>>(x, centers, labels, accum, N);
    center_loss_finalize<<<1, 64, 0, stream>>>(accum, out, 1.0f / (float)N,
                                               (float)(C - 1) * 1e-12f);
}

// Round 2
// 11.190 us; speedup vs baseline: 3.7218x; 3.7218x over previous
//
#include <hip/hip_runtime.h>

// loss = (1/N) * sum_n clip(||x_n - c_{label_n}||^2, 1e-12, 1e12)  +  (C-1)*1e-12
// (off-diagonal masked entries are exactly 0 -> clamped to 1e-12; there are N*(C-1),
//  divided by N gives (C-1)*1e-12)

#define NWAVES 2048   // partial-kernel wave count; ws[] slot per wave

__global__ void center_loss_partial(const float* __restrict__ x,
                                    const float* __restrict__ centers,
                                    const int* __restrict__ labels,
                                    float* __restrict__ partials,
                                    int N) {
    const int gtid = blockIdx.x * blockDim.x + threadIdx.x;
    const int wave = gtid >> 6;
    const int lane = threadIdx.x & 63;

    float acc = 0.0f;
    for (int row = wave; row < N; row += NWAVES) {
        const int c = labels[row];
        // D = 128 floats/row: each lane takes a float2 -> 512B coalesced per wave
        const float2 xv = *reinterpret_cast<const float2*>(x + (size_t)row * 128 + lane * 2);
        const float2 cv = *reinterpret_cast<const float2*>(centers + (size_t)c * 128 + lane * 2);
        const float d0 = xv.x - cv.x;
        const float d1 = xv.y - cv.y;
        float d = d0 * d0 + d1 * d1;
        #pragma unroll
        for (int off = 32; off; off >>= 1) d += __shfl_down(d, off, 64);
        if (lane == 0) acc += fminf(fmaxf(d, 1e-12f), 1e12f);
    }
    if (lane == 0) partials[wave] = acc;   // plain store, no init required
}

__global__ void center_loss_finalize(const float* __restrict__ partials,
                                     float* __restrict__ out,
                                     float invN, float floor_term) {
    __shared__ float warp_sums[4];
    const int tid  = threadIdx.x;          // 256 threads = 4 waves
    const int lane = tid & 63;
    const int wid  = tid >> 6;

    float s = 0.0f;
    #pragma unroll
    for (int i = 0; i < NWAVES / 256; ++i)
        s += partials[tid + i * 256];
    #pragma unroll
    for (int off = 32; off; off >>= 1) s += __shfl_down(s, off, 64);
    if (lane == 0) warp_sums[wid] = s;
    __syncthreads();
    if (tid == 0) {
        float t = warp_sums[0] + warp_sums[1] + warp_sums[2] + warp_sums[3];
        out[0] = t * invN + floor_term;
    }
}

extern "C" void kernel_launch(void* const* d_in, const int* in_sizes, int n_in,
                              void* d_out, int out_size, void* d_ws, size_t ws_size,
                              hipStream_t stream) {
    const float* x       = (const float*)d_in[0];
    const float* centers = (const float*)d_in[1];
    const int*   labels  = (const int*)d_in[2];
    float* out      = (float*)d_out;
    float* partials = (float*)d_ws;

    const int D = 128;
    const int N = in_sizes[0] / D;   // 16384
    const int C = in_sizes[1] / D;   // 1024

    const int block = 256;                  // 4 waves/block
    const int grid  = NWAVES / 4;           // 512 blocks -> 2048 waves, 8 rows/wave
    center_loss_partial<<<grid, block, 0, stream>>>(x, centers, labels, partials, N);
    center_loss_finalize<<<1, 256, 0, stream>>>(partials, out, 1.0f / (float)N,
                                                (float)(C - 1) * 1e-12f);
}